// Round 18
// baseline (548.528 us; speedup 1.0000x reference)
//
#include <hip/hip_runtime.h>
#include <math.h>

#define ALPHA_ 0.2f
#define AS1 __attribute__((address_space(1)))
#define AS3 __attribute__((address_space(3)))

constexpr int B_ = 8, LATENT_ = 256, T_ = 128, N_ = 768, F_ = 4, L_ = 3, E_ = 12288;
constexpr int M_ = B_ * N_;        // 6144 nodes
constexpr int MT_ = B_ * T_;       // 1024
constexpr int EP_ = E_ + M_;       // 18432 edges incl self loops
constexpr int BTN_ = B_ * T_ * N_; // 786432
constexpr size_t SZ_ = (size_t)BTN_ * F_;  // 3145728
constexpr int KTCN_ = 5 * N_;      // 3840
constexpr int KSPLIT_ = KTCN_ / 2; // 1920 (split-K=2, proven R7/R8)
constexpr int TP_ = T_ + 4;        // padded time dim (4 zero rows for causal)

typedef __bf16 bf16x8 __attribute__((ext_vector_type(8)));
typedef float f32x4 __attribute__((ext_vector_type(4)));

__device__ __forceinline__ float lrelu(float x) { return x > 0.0f ? x : ALPHA_ * x; }
__device__ __forceinline__ unsigned short f2bf(float x) {
    union { __bf16 h; unsigned short u; } c; c.h = (__bf16)x; return c.u;
}
__device__ __forceinline__ float bf2f(unsigned short u) {
    return __uint_as_float(((unsigned)u) << 16);
}
__device__ __forceinline__ float bflo(unsigned u) { return __uint_as_float(u << 16); }
__device__ __forceinline__ float bfhi(unsigned u) { return __uint_as_float(u & 0xffff0000u); }

// ---------------- shunt ----------------
__global__ void k_dense(const float* __restrict__ x, const float* __restrict__ w,
                        const float* __restrict__ b, float* __restrict__ y0) {
    int i = blockIdx.x * blockDim.x + threadIdx.x;
    if (i >= B_ * T_) return;
    int bb = i / T_, t = i % T_;
    float acc = b[t];
    for (int l = 0; l < LATENT_; ++l) acc += x[bb * LATENT_ + l] * w[l * T_ + t];
    y0[i] = acc;
}

__global__ void k_conv1(const float* __restrict__ y0, const float* __restrict__ w,
                        const float* __restrict__ b, float* __restrict__ y1) {
    int i = blockIdx.x * blockDim.x + threadIdx.x;
    if (i >= BTN_) return;
    int n = i % N_, t = (i / N_) % T_, bb = i / (N_ * T_);
    float acc = b[n];
    #pragma unroll
    for (int k = 0; k < 3; ++k) {
        int tt = t - 1 + k;
        if (tt >= 0 && tt < T_) acc += y0[bb * T_ + tt] * w[k * N_ + n];
    }
    y1[i] = acc;
}

// conv2 + write fp32 interleaved y AND bf16 padded planes for TCN A
__global__ void k_conv2w(const float* __restrict__ y1, const float* __restrict__ w,
                         const float* __restrict__ b, float* __restrict__ y,
                         unsigned short* __restrict__ xTpad) {
    int i = blockIdx.x * blockDim.x + threadIdx.x;
    if (i >= BTN_) return;
    int n = i % N_, t = (i / N_) % T_, bb = i / (N_ * T_);
    float acc[F_];
    #pragma unroll
    for (int f = 0; f < F_; ++f) acc[f] = b[f];
    #pragma unroll
    for (int dt = 0; dt < 3; ++dt) {
        int tt = t - 1 + dt;
        if (tt < 0 || tt >= T_) continue;
        #pragma unroll
        for (int dn = 0; dn < 3; ++dn) {
            int nn = n - 1 + dn;
            if (nn < 0 || nn >= N_) continue;
            float v = y1[(bb * T_ + tt) * N_ + nn];
            #pragma unroll
            for (int f = 0; f < F_; ++f) acc[f] += v * w[(dt * 3 + dn) * F_ + f];
        }
    }
    #pragma unroll
    for (int f = 0; f < F_; ++f) {
        y[(size_t)i * F_ + f] = acc[f];
        xTpad[((size_t)(f * B_ + bb) * TP_ + 4 + t) * N_ + n] = f2bf(acc[f]);
    }
}

// fused a/b TCN weight convert+retile v7: full-width k-slab per block. (FROZEN)
// grid (KTCN/32 = 120, 8*L); blockIdx.y = layer*8 + wsel*4 + f
__global__ __launch_bounds__(256) void k_convT2(const float* __restrict__ aw,
        const float* __restrict__ bw, unsigned short* __restrict__ wat3,
        unsigned short* __restrict__ wbt3) {
    constexpr int S_ = 770;                   // LDS row stride (ushorts); S_/2 odd
    __shared__ unsigned short tl[32 * S_];    // 49280 B, [k_local][n]
    const int z = blockIdx.y;
    const int f = z & 3, wsel = (z >> 2) & 1, layer = z >> 3;
    const size_t toff = ((size_t)layer * F_ + f) * (size_t)KTCN_ * N_;
    const float* in = (wsel ? bw : aw) + toff + (size_t)blockIdx.x * 32 * N_;
    unsigned short* outP = (wsel ? wbt3 : wat3) + toff + (size_t)blockIdx.x * (N_ * 32);
    const int tid = threadIdx.x;
    #pragma unroll
    for (int p = 0; p < 24; ++p) {
        const int flat = p * 256 + tid;       // float4 index 0..6143
        const int k = flat / 192;             // 192 float4 per 768-row
        const int nf = flat - k * 192;
        const float4 v = *(const float4*)(in + (size_t)k * N_ + nf * 4);
        const unsigned int lo = ((unsigned)f2bf(v.y) << 16) | f2bf(v.x);
        const unsigned int hi = ((unsigned)f2bf(v.w) << 16) | f2bf(v.z);
        unsigned int* dst = (unsigned int*)&tl[k * S_ + nf * 4];
        dst[0] = lo;
        dst[1] = hi;
    }
    __syncthreads();
    #pragma unroll
    for (int q = 0; q < 12; ++q) {
        const int flat = q * 256 + tid;       // 16B chunk index 0..3071
        const int n = flat >> 2;
        const int cc = flat & 3;
        const int o = cc ^ ((n >> 1) & 3);
        unsigned short pk[8];
        #pragma unroll
        for (int j = 0; j < 8; ++j) pk[j] = tl[(o * 8 + j) * S_ + n];
        *(uint4*)(outP + (size_t)n * 32 + cc * 8) = *(uint4*)pk;
    }
}

// fused Q/K/V proj weight transpose, ALL layers; z = layer*12 + sel*4 + f
// grid (T/32, T/32, 12*L)
__global__ __launch_bounds__(256) void k_convTproj(const float* __restrict__ qw,
        const float* __restrict__ kw, const float* __restrict__ vw,
        unsigned short* __restrict__ pwt3) {
    __shared__ float tl[32][33];
    const int z = blockIdx.z;
    const int f = z & 3;
    const int sel = (z >> 2) % 3;
    const int layer = z / 12;
    const float* in = (sel == 0 ? qw : (sel == 1 ? kw : vw))
                      + ((size_t)layer * F_ + f) * T_ * T_;
    unsigned short* outT = pwt3 + (((size_t)layer * 3 + sel) * F_ + f) * T_ * T_;
    const int x0 = blockIdx.x * 32;   // n
    const int y0 = blockIdx.y * 32;   // k
    const int tx = threadIdx.x & 31, ty = threadIdx.x >> 5;
    #pragma unroll
    for (int r = 0; r < 4; ++r)
        tl[ty + r * 8][tx] = in[(size_t)(y0 + ty + r * 8) * T_ + x0 + tx];
    __syncthreads();
    #pragma unroll
    for (int r = 0; r < 4; ++r)
        outT[(size_t)(x0 + ty + r * 8) * T_ + y0 + tx] = f2bf(tl[tx][ty + r * 8]);
}

// ---------------- TCN GEMM (bf16 MFMA, gl_lds, 128x128, split-K=2, 2-phase dbuf;
// B from [kc][n][32] pre-swizzled planes: linear staging, contiguous 8KB reads) ---
// 1-D grid 768: bid = c + 96*bt (bt-stride 96 == 0 mod 8 -> W-panel sharing on XCD)
__global__ __launch_bounds__(256) void k_tcn_mfma(
        const unsigned short* __restrict__ xTpad,
        const unsigned short* __restrict__ wat, const unsigned short* __restrict__ wbt,
        const float* __restrict__ ba, const float* __restrict__ bbias,
        unsigned short* __restrict__ pa, unsigned short* __restrict__ pb) {
    __shared__ unsigned short As[2][128 * 32];
    __shared__ unsigned short Bs[2][128 * 32];
    const int bid = blockIdx.x;
    const int bt = bid / 96;                         // m-tile == one batch
    const int c = bid - bt * 96;
    const int xb = c % 6;
    const int zz = c / 6;                            // 0..15
    const int f = zz & 3;
    const int wsel = (zz >> 2) & 1;
    const int s = zz >> 3;                           // 0..1
    const int n0 = xb * 128;
    const unsigned short* xf = xTpad + (size_t)(f * B_ + bt) * TP_ * N_;
    const unsigned short* wfp = (wsel ? wbt : wat) + (size_t)f * KTCN_ * N_;
    const float* bias = (wsel ? bbias : ba) + f * N_;
    unsigned short* out = (wsel ? pb : pa) + (size_t)s * SZ_;
    const int tid = threadIdx.x;
    const int lane = tid & 63;
    const int w = tid >> 6;
    const int wm = (w >> 1) * 64, wn = (w & 1) * 64;
    const int r16 = lane & 15, kb = lane >> 4;
    const int srow = lane >> 2;                      // 0..15
    const int scol = (((lane & 3) ^ ((lane >> 3) & 3)) * 8);   // A source swizzle
    const int bcol = (lane & 3) * 8;                 // B source LINEAR (pre-swizzled)
    const int kx = (kb ^ ((r16 >> 1) & 3)) * 8;      // fragment read swizzle
    const int k_lo = s * KSPLIT_, k_hi = k_lo + KSPLIT_;

    auto stage = [&](int buf, int kk0) {
        const int ks = kk0 / N_;                     // 32|768 -> constant per chunk
        const int nin0 = kk0 - ks * N_;
        const unsigned short* plane = wfp + (size_t)(kk0 >> 5) * (N_ * 32);
        #pragma unroll
        for (int h = 0; h < 2; ++h) {
            const int seg = w + 4 * h;
            const int row = seg * 16 + srow;
            const unsigned short* gA = xf + (size_t)(row + ks) * N_ + nin0 + scol;
            const unsigned short* gB = plane + (size_t)(n0 + row) * 32 + bcol;
            __builtin_amdgcn_global_load_lds((const AS1 unsigned int*)(const void*)gA,
                    (AS3 unsigned int*)(void*)(&As[buf][seg * 512]), 16, 0, 0);
            __builtin_amdgcn_global_load_lds((const AS1 unsigned int*)(const void*)gB,
                    (AS3 unsigned int*)(void*)(&Bs[buf][seg * 512]), 16, 0, 0);
        }
    };

    f32x4 acc[4][4] = {};
    stage(0, k_lo);
    __syncthreads();                                 // drain prologue
    int cur = 0;
    for (int kk0 = k_lo; kk0 < k_hi; kk0 += 32) {
        if (kk0 + 32 < k_hi) stage(cur ^ 1, kk0 + 32);   // issue next tile's loads
        bf16x8 av[4], bv[4];
        #pragma unroll
        for (int i = 0; i < 4; ++i)
            av[i] = *(const bf16x8*)(&As[cur][(wm + i * 16 + r16) * 32 + kx]);
        #pragma unroll
        for (int j = 0; j < 4; ++j)
            bv[j] = *(const bf16x8*)(&Bs[cur][(wn + j * 16 + r16) * 32 + kx]);
        #pragma unroll
        for (int i = 0; i < 4; ++i)
            #pragma unroll
            for (int j = 0; j < 4; ++j)
                acc[i][j] = __builtin_amdgcn_mfma_f32_16x16x32_bf16(av[i], bv[j], acc[i][j], 0, 0, 0);
        __syncthreads();                             // drains next-tile vmcnt + barrier
        cur ^= 1;
    }
    unsigned short* of = out + (size_t)(f * B_ + bt) * T_ * N_;
    #pragma unroll
    for (int i = 0; i < 4; ++i) {
        #pragma unroll
        for (int j = 0; j < 4; ++j) {
            const int n = n0 + wn + j * 16 + r16;
            const float bv2 = (s == 0) ? bias[n] : 0.0f;
            #pragma unroll
            for (int r = 0; r < 4; ++r) {
                const int m = wm + i * 16 + kb * 4 + r;
                of[(size_t)m * N_ + n] = f2bf(acc[i][j][r] + bv2);
            }
        }
    }
}

// ---------------- gating (sum 2 bf16 split-K partials) + transpose, VECTORIZED ----
// grid (T/32, N/32, F*B); uint2 (4 bf16) loads and stores
__global__ __launch_bounds__(256) void k_gate_nodes(const unsigned short* __restrict__ pa,
        const unsigned short* __restrict__ pb, unsigned short* __restrict__ nodes) {
    __shared__ float tl[32][33];
    const int bz = blockIdx.z;                       // f*B + b
    const int t0 = blockIdx.x * 32, n0 = blockIdx.y * 32;
    const size_t base = (size_t)bz * T_ * N_;
    {
        const int r = threadIdx.x >> 3;              // t row 0..31
        const int c = threadIdx.x & 7;               // n chunk of 4
        const size_t idx = base + (size_t)(t0 + r) * N_ + n0 + c * 4;
        const uint2 A0 = *(const uint2*)(pa + idx);
        const uint2 A1 = *(const uint2*)(pa + SZ_ + idx);
        const uint2 B0 = *(const uint2*)(pb + idx);
        const uint2 B1 = *(const uint2*)(pb + SZ_ + idx);
        const float av[4] = {bflo(A0.x) + bflo(A1.x), bfhi(A0.x) + bfhi(A1.x),
                             bflo(A0.y) + bflo(A1.y), bfhi(A0.y) + bfhi(A1.y)};
        const float bv[4] = {bflo(B0.x) + bflo(B1.x), bfhi(B0.x) + bfhi(B1.x),
                             bflo(B0.y) + bflo(B1.y), bfhi(B0.y) + bfhi(B1.y)};
        #pragma unroll
        for (int j = 0; j < 4; ++j)
            tl[r][c * 4 + j] = (1.0f / (1.0f + __expf(-av[j]))) * tanhf(bv[j]);
    }
    __syncthreads();
    {
        const int nr = threadIdx.x >> 3;             // n row 0..31
        const int tc = threadIdx.x & 7;              // t chunk of 4
        unsigned short pk[4];
        #pragma unroll
        for (int j = 0; j < 4; ++j) pk[j] = f2bf(tl[tc * 4 + j][nr]);
        *(uint2*)(nodes + base + (size_t)(n0 + nr) * T_ + t0 + tc * 4) = *(uint2*)pk;
    }
}

// ---------------- GAT projection GEMM (gl_lds, swizzled, Q/K/V fused, bf16 out,
// 2-phase double-buffer) ------------------------------------------------------------
__global__ __launch_bounds__(256) void k_proj_mfma(
        const unsigned short* __restrict__ nodes, const unsigned short* __restrict__ pwt,
        const float* __restrict__ qb, const float* __restrict__ kbias,
        unsigned short* __restrict__ Q, unsigned short* __restrict__ K,
        unsigned short* __restrict__ V) {
    __shared__ unsigned short As[2][128 * 32];
    __shared__ unsigned short Bs[2][128 * 32];
    const int zz = blockIdx.z;
    const int f = zz & 3;
    const int sel = zz >> 2;
    const int m0 = blockIdx.y * 128;
    const unsigned short* af = nodes + (size_t)f * M_ * T_;
    const unsigned short* wfp = pwt + (size_t)sel * F_ * T_ * T_ + (size_t)f * T_ * T_;
    const float* bias = (sel == 0) ? qb : (sel == 1 ? kbias : nullptr);
    unsigned short* out = (sel == 0) ? Q : (sel == 1 ? K : V);
    const int tid = threadIdx.x;
    const int lane = tid & 63;
    const int w = tid >> 6;
    const int wm = (w >> 1) * 64, wn = (w & 1) * 64;
    const int r16 = lane & 15, kb = lane >> 4;
    const int srow = lane >> 2;
    const int scol = (((lane & 3) ^ ((lane >> 3) & 3)) * 8);
    const int kx = (kb ^ ((r16 >> 1) & 3)) * 8;

    auto stage = [&](int buf, int kk0) {
        #pragma unroll
        for (int h = 0; h < 2; ++h) {
            const int seg = w + 4 * h;
            const int row = seg * 16 + srow;
            const unsigned short* gA = af + (size_t)(m0 + row) * T_ + kk0 + scol;
            const unsigned short* gB = wfp + (size_t)row * T_ + kk0 + scol;
            __builtin_amdgcn_global_load_lds((const AS1 unsigned int*)(const void*)gA,
                    (AS3 unsigned int*)(void*)(&As[buf][seg * 512]), 16, 0, 0);
            __builtin_amdgcn_global_load_lds((const AS1 unsigned int*)(const void*)gB,
                    (AS3 unsigned int*)(void*)(&Bs[buf][seg * 512]), 16, 0, 0);
        }
    };

    f32x4 acc[4][4] = {};
    stage(0, 0);
    __syncthreads();
    int cur = 0;
    for (int kk0 = 0; kk0 < T_; kk0 += 32) {
        if (kk0 + 32 < T_) stage(cur ^ 1, kk0 + 32);
        bf16x8 av[4], bv[4];
        #pragma unroll
        for (int i = 0; i < 4; ++i)
            av[i] = *(const bf16x8*)(&As[cur][(wm + i * 16 + r16) * 32 + kx]);
        #pragma unroll
        for (int j = 0; j < 4; ++j)
            bv[j] = *(const bf16x8*)(&Bs[cur][(wn + j * 16 + r16) * 32 + kx]);
        #pragma unroll
        for (int i = 0; i < 4; ++i)
            #pragma unroll
            for (int j = 0; j < 4; ++j)
                acc[i][j] = __builtin_amdgcn_mfma_f32_16x16x32_bf16(av[i], bv[j], acc[i][j], 0, 0, 0);
        __syncthreads();
        cur ^= 1;
    }
    const int do_l = (sel < 2);
    unsigned short* of = out + (size_t)f * M_ * T_;
    #pragma unroll
    for (int i = 0; i < 4; ++i) {
        #pragma unroll
        for (int j = 0; j < 4; ++j) {
            const int n = wn + j * 16 + r16;
            #pragma unroll
            for (int r = 0; r < 4; ++r) {
                const int m = m0 + wm + i * 16 + kb * 4 + r;
                float v = acc[i][j][r];
                if (bias) v += bias[f * T_ + n];
                if (do_l) v = lrelu(v);
                of[(size_t)m * T_ + n] = f2bf(v);
            }
        }
    }
}

// ---------------- CSR build (once; graph shared across f and layers) --------------
__device__ __forceinline__ int edge_row(const int* e, int i) { return i < E_ ? e[i] : i - E_; }
__device__ __forceinline__ int edge_col(const int* e, int i) { return i < E_ ? e[E_ + i] : i - E_; }

__global__ void k_hist(const int* __restrict__ edges, int* __restrict__ deg) {
    int i = blockIdx.x * blockDim.x + threadIdx.x;
    if (i >= EP_) return;
    atomicAdd(&deg[edge_row(edges, i)], 1);
}

__global__ __launch_bounds__(256) void k_scan(const int* __restrict__ deg,
        int* __restrict__ rowptr, int* __restrict__ cursor) {
    __shared__ int part[256];
    const int tid = threadIdx.x;
    constexpr int PER = M_ / 256;   // 24
    int loc[PER];
    int s = 0;
    #pragma unroll
    for (int j = 0; j < PER; ++j) { loc[j] = s; s += deg[tid * PER + j]; }
    part[tid] = s;
    __syncthreads();
    if (tid == 0) {
        int run = 0;
        for (int i2 = 0; i2 < 256; ++i2) { int v = part[i2]; part[i2] = run; run += v; }
        rowptr[M_] = run;
    }
    __syncthreads();
    const int off = part[tid];
    #pragma unroll
    for (int j = 0; j < PER; ++j) {
        rowptr[tid * PER + j] = off + loc[j];
        cursor[tid * PER + j] = off + loc[j];
    }
}

__global__ void k_scatter(const int* __restrict__ edges, int* __restrict__ cursor,
                          int* __restrict__ csr_col) {
    int i = blockIdx.x * blockDim.x + threadIdx.x;
    if (i >= EP_) return;
    int r = edge_row(edges, i), c = edge_col(edges, i);
    int pos = atomicAdd(&cursor[r], 1);
    csr_col[pos] = c;
}

// ---------------- fused GAT (bf16 Q/K/V, bf16 H out), VECTORIZED: lane owns a
// t-pair (uint = 2 bf16 per access); one wave per (f,row); deg==1 fast path -------
__global__ __launch_bounds__(256) void k_gat(const unsigned short* __restrict__ Q,
        const unsigned short* __restrict__ Kb, const unsigned short* __restrict__ V,
        const int* __restrict__ rowptr, const int* __restrict__ csr_col,
        unsigned short* __restrict__ H) {
    constexpr int CAP = 128;
    __shared__ float sc[4][CAP];
    const int w = threadIdx.x >> 6, lane = threadIdx.x & 63;
    const int wv = blockIdx.x * 4 + w;
    const int f = wv / M_, r = wv - f * M_;
    const int p0 = rowptr[r], p1 = rowptr[r + 1];
    unsigned short* Hr = H + ((size_t)f * M_ + r) * T_;
    if (p1 - p0 == 1) {   // self-loop only: att == 1, H = V[r]
        const unsigned short* Vr = V + ((size_t)f * M_ + r) * T_;
        *(unsigned*)(Hr + 2 * lane) = *(const unsigned*)(Vr + 2 * lane);
        return;
    }
    const unsigned short* Qr = Q + ((size_t)f * M_ + r) * T_;
    const unsigned qv = *(const unsigned*)(Qr + 2 * lane);
    const float q0 = bflo(qv), q1 = bfhi(qv);
    float mx = -3.4e38f;
    for (int j = p0; j < p1; ++j) {
        const unsigned short* Kc = Kb + ((size_t)f * M_ + csr_col[j]) * T_;
        const unsigned kv = *(const unsigned*)(Kc + 2 * lane);
        float s = q0 * bflo(kv) + q1 * bfhi(kv);
        #pragma unroll
        for (int mk = 32; mk >= 1; mk >>= 1) s += __shfl_xor(s, mk);
        s *= 0.0883883476483184f;
        if (lane == 0) sc[w][j - p0] = s;   // deg << CAP always
        mx = fmaxf(mx, s);
    }
    float den = 0.0f;
    for (int j = p0; j < p1; ++j) den += __expf(sc[w][j - p0] - mx);
    const float rden = 1.0f / den;
    float a0 = 0.0f, a1 = 0.0f;
    for (int j = p0; j < p1; ++j) {
        const int c = csr_col[j];
        const float att = __expf(sc[w][j - p0] - mx) * rden;
        const unsigned short* Vc = V + ((size_t)f * M_ + c) * T_;
        const unsigned vv = *(const unsigned*)(Vc + 2 * lane);
        a0 += att * bflo(vv);
        a1 += att * bfhi(vv);
    }
    *(unsigned*)(Hr + 2 * lane) = (unsigned)f2bf(a0) | ((unsigned)f2bf(a1) << 16);
}

// ---------------- combine: residual + skip + bf16 xTpad, VECTORIZED ---------------
// grid (T/32, N/32, B); uint2 H loads, float4 y/ynext/sbufp, uint2 xTpad writes
__global__ __launch_bounds__(256) void k_combine_t(const float* __restrict__ y,
        const unsigned short* __restrict__ H, const float* __restrict__ vb,
        const float* __restrict__ rw, const float* __restrict__ rb,
        const float* __restrict__ skw, const float* __restrict__ skb, int layer,
        float* __restrict__ ynext, unsigned short* __restrict__ xTpad,
        float* __restrict__ sbufp) {
    __shared__ float hl[F_][32][33];
    const int b = blockIdx.z;
    const int t0 = blockIdx.x * 32, n0 = blockIdx.y * 32;
    {
        const int nn = threadIdx.x >> 3;             // n row 0..31
        const int tc = threadIdx.x & 7;              // t chunk of 4
        #pragma unroll
        for (int g = 0; g < F_; ++g) {
            const uint2 hv = *(const uint2*)(H +
                ((size_t)g * M_ + b * N_ + n0 + nn) * T_ + t0 + tc * 4);
            hl[g][nn][tc * 4 + 0] = bflo(hv.x);
            hl[g][nn][tc * 4 + 1] = bfhi(hv.x);
            hl[g][nn][tc * 4 + 2] = bflo(hv.y);
            hl[g][nn][tc * 4 + 3] = bfhi(hv.y);
        }
    }
    __syncthreads();
    const int r = threadIdx.x >> 3;                  // t row 0..31
    const int nc = threadIdx.x & 7;                  // n chunk of 4
    const int t = t0 + r;
    const size_t ibase = ((size_t)b * T_ + t) * N_ + n0 + nc * 4;
    float o[4][F_];
    float sbv[4];
    #pragma unroll
    for (int q = 0; q < 4; ++q) {
        const float4 y4 = *(const float4*)(y + (ibase + q) * 4);
        #pragma unroll
        for (int g = 0; g < F_; ++g) {
            float acc = hl[g][nc * 4 + q][r] + vb[g * T_ + t] + rb[g];
            acc += y4.x * rw[0 * F_ + g] + y4.y * rw[1 * F_ + g]
                 + y4.z * rw[2 * F_ + g] + y4.w * rw[3 * F_ + g];
            o[q][g] = acc;
        }
        float4 o4 = {o[q][0], o[q][1], o[q][2], o[q][3]};
        *(float4*)(ynext + (ibase + q) * 4) = o4;
        float sk = skb[layer];
        #pragma unroll
        for (int g = 0; g < F_; ++g) sk += o[q][g] * skw[layer * F_ + g];
        sbv[q] = lrelu(sk);
    }
    #pragma unroll
    for (int g = 0; g < F_; ++g) {
        unsigned short pk[4];
        #pragma unroll
        for (int q = 0; q < 4; ++q) pk[q] = f2bf(o[q][g]);
        *(uint2*)(xTpad + ((size_t)(g * B_ + b) * TP_ + 4 + t) * N_ + n0 + nc * 4)
            = *(uint2*)pk;
    }
    float4 s4 = {sbv[0], sbv[1], sbv[2], sbv[3]};
    *(float4*)(sbufp + (size_t)layer * BTN_ + ibase) = s4;
}

__global__ void k_final(const float* __restrict__ sbufp, const float* __restrict__ o1w,
        const float* __restrict__ o1b, const float* __restrict__ o2w,
        const float* __restrict__ o2b, float* __restrict__ out) {
    int i = blockIdx.x * blockDim.x + threadIdx.x;
    if (i >= BTN_) return;
    int n = i % N_, t = (i / N_) % T_, bb = i / (N_ * T_);
    float acc = o1b[0];
    #pragma unroll
    for (int dt = 0; dt < 3; ++dt) {
        int tt = t - 1 + dt;
        if (tt < 0 || tt >= T_) continue;
        #pragma unroll
        for (int dn = 0; dn < 3; ++dn) {
            int nn = n - 1 + dn;
            if (nn < 0 || nn >= N_) continue;
            const size_t base = (size_t)(bb * T_ + tt) * N_ + nn;
            #pragma unroll
            for (int l = 0; l < L_; ++l)
                acc += sbufp[(size_t)l * BTN_ + base] * o1w[(dt * 3 + dn) * L_ + l];
        }
    }
    float g = lrelu(acc);
    out[i] = g * o2w[0] + o2b[0];
}

extern "C" void kernel_launch(void* const* d_in, const int* in_sizes, int n_in,
                              void* d_out, int out_size, void* d_ws, size_t ws_size,
                              hipStream_t stream) {
    const float* x       = (const float*)d_in[0];
    const int*   edges   = (const int*)d_in[1];
    const float* sd_w    = (const float*)d_in[2];
    const float* sd_b    = (const float*)d_in[3];
    const float* c1w     = (const float*)d_in[4];
    const float* c1b     = (const float*)d_in[5];
    const float* c2w     = (const float*)d_in[6];
    const float* c2b     = (const float*)d_in[7];
    const float* tcn_a_w = (const float*)d_in[8];
    const float* tcn_a_b = (const float*)d_in[9];
    const float* tcn_b_w = (const float*)d_in[10];
    const float* tcn_b_b = (const float*)d_in[11];
    const float* gat_q_w = (const float*)d_in[12];
    const float* gat_q_b = (const float*)d_in[13];
    const float* gat_k_w = (const float*)d_in[14];
    const float* gat_k_b = (const float*)d_in[15];
    const float* gat_v_w = (const float*)d_in[16];
    const float* gat_v_b = (const float*)d_in[17];
    const float* res_w   = (const float*)d_in[18];
    const float* res_b   = (const float*)d_in[19];
    const float* skip_w  = (const float*)d_in[20];
    const float* skip_b  = (const float*)d_in[21];
    const float* out1_w  = (const float*)d_in[22];
    const float* out1_b  = (const float*)d_in[23];
    const float* out2_w  = (const float*)d_in[24];
    const float* out2_b  = (const float*)d_in[25];
    float* out = (float*)d_out;

    float* ws = (float*)d_ws;
    size_t off = 0;
    auto alloc = [&](size_t nf) { float* p = ws + off; off += nf; return p; };
    float* ybuf  = alloc(SZ_);
    float* y2buf = alloc(SZ_);
    float* sbufp = alloc((size_t)BTN_ * L_);
    float* y0    = alloc(MT_);
    float* y1    = alloc(BTN_);
    unsigned short* xTpad  = (unsigned short*)alloc((size_t)F_ * B_ * TP_ * N_ / 2 + 16);
    unsigned short* nodesb = (unsigned short*)alloc(SZ_ / 2);
    unsigned short* qb16   = (unsigned short*)alloc(SZ_ / 2);
    unsigned short* kb16   = (unsigned short*)alloc(SZ_ / 2);
    unsigned short* vb16   = (unsigned short*)alloc(SZ_ / 2);
    unsigned short* Hb     = (unsigned short*)alloc(SZ_ / 2);
    unsigned short* pa     = (unsigned short*)alloc(SZ_);       // 2 partial planes
    unsigned short* pb     = (unsigned short*)alloc(SZ_);       // 2 partial planes
    unsigned short* wat3 = (unsigned short*)alloc((size_t)L_ * F_ * KTCN_ * N_ / 2);
    unsigned short* wbt3 = (unsigned short*)alloc((size_t)L_ * F_ * KTCN_ * N_ / 2);
    unsigned short* pwt3 = (unsigned short*)alloc((size_t)L_ * 3 * F_ * T_ * T_ / 2);
    int* rowptr  = (int*)alloc(M_ + 1);
    int* cursor  = (int*)alloc(M_);
    int* deg     = (int*)alloc(M_);
    int* csr_col = (int*)alloc(EP_);
    (void)ws_size; (void)in_sizes; (void)n_in; (void)out_size;

    // zero padded activation buffer once (pad rows stay zero forever)
    hipMemsetAsync(xTpad, 0, (size_t)F_ * B_ * TP_ * N_ * 2, stream);
    // CSR build (graph is layer/f independent)
    hipMemsetAsync(deg, 0, M_ * 4, stream);
    k_hist<<<(EP_ + 255) / 256, 256, 0, stream>>>(edges, deg);
    k_scan<<<1, 256, 0, stream>>>(deg, rowptr, cursor);
    k_scatter<<<(EP_ + 255) / 256, 256, 0, stream>>>(edges, cursor, csr_col);

    // ALL weight prep hoisted: TCN (a/b, 3 layers) + proj (q/k/v, 3 layers)
    dim3 gw2(KTCN_ / 32, 8 * L_);
    k_convT2<<<gw2, 256, 0, stream>>>(tcn_a_w, tcn_b_w, wat3, wbt3);
    dim3 gpw(T_ / 32, T_ / 32, 12 * L_);
    k_convTproj<<<gpw, 256, 0, stream>>>(gat_q_w, gat_k_w, gat_v_w, pwt3);

    // shunt
    k_dense<<<(B_ * T_ + 255) / 256, 256, 0, stream>>>(x, sd_w, sd_b, y0);
    k_conv1<<<(BTN_ + 255) / 256, 256, 0, stream>>>(y0, c1w, c1b, y1);
    k_conv2w<<<(BTN_ + 255) / 256, 256, 0, stream>>>(y1, c2w, c2b, ybuf, xTpad);

    float* cur = ybuf;
    float* nxt = y2buf;
    for (int layer = 0; layer < L_; ++layer) {
        const float* ba = tcn_a_b + (size_t)layer * F_ * N_;
        const float* bb = tcn_b_b + (size_t)layer * F_ * N_;
        const float* qb = gat_q_b + (size_t)layer * F_ * T_;
        const float* kbias = gat_k_b + (size_t)layer * F_ * T_;
        const float* vb = gat_v_b + (size_t)layer * F_ * T_;
        const float* rw = res_w + (size_t)layer * F_ * F_;
        const float* rb = res_b + (size_t)layer * F_;
        const unsigned short* wat = wat3 + (size_t)layer * F_ * KTCN_ * N_;
        const unsigned short* wbt = wbt3 + (size_t)layer * F_ * KTCN_ * N_;
        const unsigned short* pwt = pwt3 + (size_t)layer * 3 * F_ * T_ * T_;

        // TCN GEMMs: 128x128 tile, a/b fused, split-K=2, XCD-aware 1-D grid, dbuf
        k_tcn_mfma<<<768, 256, 0, stream>>>(xTpad, wat, wbt, ba, bb, pa, pb);
        // gating (sum 2 partials) + transpose -> bf16 nodes
        dim3 gg(T_ / 32, N_ / 32, F_ * B_);
        k_gate_nodes<<<gg, 256, 0, stream>>>(pa, pb, nodesb);
        // projections fused: Q/K/V -> bf16, dbuf
        dim3 gp(1, M_ / 128, 12);
        k_proj_mfma<<<gp, 256, 0, stream>>>(nodesb, pwt, qb, kbias, qb16, kb16, vb16);
        // fused GAT (no atomics, no memsets), bf16 H, deg==1 fast path
        k_gat<<<(F_ * M_) / 4, 256, 0, stream>>>(qb16, kb16, vb16, rowptr, csr_col, Hb);
        // combine + next-layer bf16 planes + skip plane
        dim3 gc(T_ / 32, N_ / 32, B_);
        k_combine_t<<<gc, 256, 0, stream>>>(cur, Hb, vb, rw, rb, skip_w, skip_b,
                layer, nxt, xTpad, sbufp);
        float* tmp = cur; cur = nxt; nxt = tmp;
    }
    k_final<<<(BTN_ + 255) / 256, 256, 0, stream>>>(sbufp, out1_w, out1_b, out2_w, out2_b, out);
}

// Round 19
// 532.463 us; speedup vs baseline: 1.0302x; 1.0302x over previous
//
#include <hip/hip_runtime.h>
#include <math.h>

#define ALPHA_ 0.2f
#define AS1 __attribute__((address_space(1)))
#define AS3 __attribute__((address_space(3)))

constexpr int B_ = 8, LATENT_ = 256, T_ = 128, N_ = 768, F_ = 4, L_ = 3, E_ = 12288;
constexpr int M_ = B_ * N_;        // 6144 nodes
constexpr int MT_ = B_ * T_;       // 1024
constexpr int EP_ = E_ + M_;       // 18432 edges incl self loops
constexpr int BTN_ = B_ * T_ * N_; // 786432
constexpr size_t SZ_ = (size_t)BTN_ * F_;  // 3145728
constexpr int KTCN_ = 5 * N_;      // 3840
constexpr int KSPLIT_ = KTCN_ / 2; // 1920 (split-K=2, proven R7/R8)
constexpr int TP_ = T_ + 4;        // padded time dim (4 zero rows for causal)

typedef __bf16 bf16x8 __attribute__((ext_vector_type(8)));
typedef float f32x4 __attribute__((ext_vector_type(4)));

__device__ __forceinline__ float lrelu(float x) { return x > 0.0f ? x : ALPHA_ * x; }
__device__ __forceinline__ unsigned short f2bf(float x) {
    union { __bf16 h; unsigned short u; } c; c.h = (__bf16)x; return c.u;
}
__device__ __forceinline__ float bf2f(unsigned short u) {
    return __uint_as_float(((unsigned)u) << 16);
}
__device__ __forceinline__ float bflo(unsigned u) { return __uint_as_float(u << 16); }
__device__ __forceinline__ float bfhi(unsigned u) { return __uint_as_float(u & 0xffff0000u); }

// ---------------- shunt ----------------
__global__ void k_dense(const float* __restrict__ x, const float* __restrict__ w,
                        const float* __restrict__ b, float* __restrict__ y0) {
    int i = blockIdx.x * blockDim.x + threadIdx.x;
    if (i >= B_ * T_) return;
    int bb = i / T_, t = i % T_;
    float acc = b[t];
    for (int l = 0; l < LATENT_; ++l) acc += x[bb * LATENT_ + l] * w[l * T_ + t];
    y0[i] = acc;
}

__global__ void k_conv1(const float* __restrict__ y0, const float* __restrict__ w,
                        const float* __restrict__ b, float* __restrict__ y1) {
    int i = blockIdx.x * blockDim.x + threadIdx.x;
    if (i >= BTN_) return;
    int n = i % N_, t = (i / N_) % T_, bb = i / (N_ * T_);
    float acc = b[n];
    #pragma unroll
    for (int k = 0; k < 3; ++k) {
        int tt = t - 1 + k;
        if (tt >= 0 && tt < T_) acc += y0[bb * T_ + tt] * w[k * N_ + n];
    }
    y1[i] = acc;
}

// conv2 -> bf16 padded planes ONLY (y fp32 carrier eliminated; residual reads xTpad)
__global__ void k_conv2w(const float* __restrict__ y1, const float* __restrict__ w,
                         const float* __restrict__ b, unsigned short* __restrict__ xTpad) {
    int i = blockIdx.x * blockDim.x + threadIdx.x;
    if (i >= BTN_) return;
    int n = i % N_, t = (i / N_) % T_, bb = i / (N_ * T_);
    float acc[F_];
    #pragma unroll
    for (int f = 0; f < F_; ++f) acc[f] = b[f];
    #pragma unroll
    for (int dt = 0; dt < 3; ++dt) {
        int tt = t - 1 + dt;
        if (tt < 0 || tt >= T_) continue;
        #pragma unroll
        for (int dn = 0; dn < 3; ++dn) {
            int nn = n - 1 + dn;
            if (nn < 0 || nn >= N_) continue;
            float v = y1[(bb * T_ + tt) * N_ + nn];
            #pragma unroll
            for (int f = 0; f < F_; ++f) acc[f] += v * w[(dt * 3 + dn) * F_ + f];
        }
    }
    #pragma unroll
    for (int f = 0; f < F_; ++f)
        xTpad[((size_t)(f * B_ + bb) * TP_ + 4 + t) * N_ + n] = f2bf(acc[f]);
}

// fused a/b TCN weight convert+retile v7: full-width k-slab per block. (FROZEN)
// grid (KTCN/32 = 120, 8*L); blockIdx.y = layer*8 + wsel*4 + f
__global__ __launch_bounds__(256) void k_convT2(const float* __restrict__ aw,
        const float* __restrict__ bw, unsigned short* __restrict__ wat3,
        unsigned short* __restrict__ wbt3) {
    constexpr int S_ = 770;                   // LDS row stride (ushorts); S_/2 odd
    __shared__ unsigned short tl[32 * S_];    // 49280 B, [k_local][n]
    const int z = blockIdx.y;
    const int f = z & 3, wsel = (z >> 2) & 1, layer = z >> 3;
    const size_t toff = ((size_t)layer * F_ + f) * (size_t)KTCN_ * N_;
    const float* in = (wsel ? bw : aw) + toff + (size_t)blockIdx.x * 32 * N_;
    unsigned short* outP = (wsel ? wbt3 : wat3) + toff + (size_t)blockIdx.x * (N_ * 32);
    const int tid = threadIdx.x;
    #pragma unroll
    for (int p = 0; p < 24; ++p) {
        const int flat = p * 256 + tid;       // float4 index 0..6143
        const int k = flat / 192;             // 192 float4 per 768-row
        const int nf = flat - k * 192;
        const float4 v = *(const float4*)(in + (size_t)k * N_ + nf * 4);
        const unsigned int lo = ((unsigned)f2bf(v.y) << 16) | f2bf(v.x);
        const unsigned int hi = ((unsigned)f2bf(v.w) << 16) | f2bf(v.z);
        unsigned int* dst = (unsigned int*)&tl[k * S_ + nf * 4];
        dst[0] = lo;
        dst[1] = hi;
    }
    __syncthreads();
    #pragma unroll
    for (int q = 0; q < 12; ++q) {
        const int flat = q * 256 + tid;       // 16B chunk index 0..3071
        const int n = flat >> 2;
        const int cc = flat & 3;
        const int o = cc ^ ((n >> 1) & 3);
        unsigned short pk[8];
        #pragma unroll
        for (int j = 0; j < 8; ++j) pk[j] = tl[(o * 8 + j) * S_ + n];
        *(uint4*)(outP + (size_t)n * 32 + cc * 8) = *(uint4*)pk;
    }
}

// fused Q/K/V proj weight transpose, ALL layers; z = layer*12 + sel*4 + f
// grid (T/32, T/32, 12*L)
__global__ __launch_bounds__(256) void k_convTproj(const float* __restrict__ qw,
        const float* __restrict__ kw, const float* __restrict__ vw,
        unsigned short* __restrict__ pwt3) {
    __shared__ float tl[32][33];
    const int z = blockIdx.z;
    const int f = z & 3;
    const int sel = (z >> 2) % 3;
    const int layer = z / 12;
    const float* in = (sel == 0 ? qw : (sel == 1 ? kw : vw))
                      + ((size_t)layer * F_ + f) * T_ * T_;
    unsigned short* outT = pwt3 + (((size_t)layer * 3 + sel) * F_ + f) * T_ * T_;
    const int x0 = blockIdx.x * 32;   // n
    const int y0 = blockIdx.y * 32;   // k
    const int tx = threadIdx.x & 31, ty = threadIdx.x >> 5;
    #pragma unroll
    for (int r = 0; r < 4; ++r)
        tl[ty + r * 8][tx] = in[(size_t)(y0 + ty + r * 8) * T_ + x0 + tx];
    __syncthreads();
    #pragma unroll
    for (int r = 0; r < 4; ++r)
        outT[(size_t)(x0 + ty + r * 8) * T_ + y0 + tx] = f2bf(tl[tx][ty + r * 8]);
}

// ---------------- TCN GEMM (bf16 MFMA, gl_lds, 128x128, split-K=2, 2-phase dbuf;
// B from [kc][n][32] pre-swizzled planes: linear staging, contiguous 8KB reads) ---
// 1-D grid 768: bid = c + 96*bt (bt-stride 96 == 0 mod 8 -> W-panel sharing on XCD)
__global__ __launch_bounds__(256) void k_tcn_mfma(
        const unsigned short* __restrict__ xTpad,
        const unsigned short* __restrict__ wat, const unsigned short* __restrict__ wbt,
        const float* __restrict__ ba, const float* __restrict__ bbias,
        unsigned short* __restrict__ pa, unsigned short* __restrict__ pb) {
    __shared__ unsigned short As[2][128 * 32];
    __shared__ unsigned short Bs[2][128 * 32];
    const int bid = blockIdx.x;
    const int bt = bid / 96;                         // m-tile == one batch
    const int c = bid - bt * 96;
    const int xb = c % 6;
    const int zz = c / 6;                            // 0..15
    const int f = zz & 3;
    const int wsel = (zz >> 2) & 1;
    const int s = zz >> 3;                           // 0..1
    const int n0 = xb * 128;
    const unsigned short* xf = xTpad + (size_t)(f * B_ + bt) * TP_ * N_;
    const unsigned short* wfp = (wsel ? wbt : wat) + (size_t)f * KTCN_ * N_;
    const float* bias = (wsel ? bbias : ba) + f * N_;
    unsigned short* out = (wsel ? pb : pa) + (size_t)s * SZ_;
    const int tid = threadIdx.x;
    const int lane = tid & 63;
    const int w = tid >> 6;
    const int wm = (w >> 1) * 64, wn = (w & 1) * 64;
    const int r16 = lane & 15, kb = lane >> 4;
    const int srow = lane >> 2;                      // 0..15
    const int scol = (((lane & 3) ^ ((lane >> 3) & 3)) * 8);   // A source swizzle
    const int bcol = (lane & 3) * 8;                 // B source LINEAR (pre-swizzled)
    const int kx = (kb ^ ((r16 >> 1) & 3)) * 8;      // fragment read swizzle
    const int k_lo = s * KSPLIT_, k_hi = k_lo + KSPLIT_;

    auto stage = [&](int buf, int kk0) {
        const int ks = kk0 / N_;                     // 32|768 -> constant per chunk
        const int nin0 = kk0 - ks * N_;
        const unsigned short* plane = wfp + (size_t)(kk0 >> 5) * (N_ * 32);
        #pragma unroll
        for (int h = 0; h < 2; ++h) {
            const int seg = w + 4 * h;
            const int row = seg * 16 + srow;
            const unsigned short* gA = xf + (size_t)(row + ks) * N_ + nin0 + scol;
            const unsigned short* gB = plane + (size_t)(n0 + row) * 32 + bcol;
            __builtin_amdgcn_global_load_lds((const AS1 unsigned int*)(const void*)gA,
                    (AS3 unsigned int*)(void*)(&As[buf][seg * 512]), 16, 0, 0);
            __builtin_amdgcn_global_load_lds((const AS1 unsigned int*)(const void*)gB,
                    (AS3 unsigned int*)(void*)(&Bs[buf][seg * 512]), 16, 0, 0);
        }
    };

    f32x4 acc[4][4] = {};
    stage(0, k_lo);
    __syncthreads();                                 // drain prologue
    int cur = 0;
    for (int kk0 = k_lo; kk0 < k_hi; kk0 += 32) {
        if (kk0 + 32 < k_hi) stage(cur ^ 1, kk0 + 32);   // issue next tile's loads
        bf16x8 av[4], bv[4];
        #pragma unroll
        for (int i = 0; i < 4; ++i)
            av[i] = *(const bf16x8*)(&As[cur][(wm + i * 16 + r16) * 32 + kx]);
        #pragma unroll
        for (int j = 0; j < 4; ++j)
            bv[j] = *(const bf16x8*)(&Bs[cur][(wn + j * 16 + r16) * 32 + kx]);
        #pragma unroll
        for (int i = 0; i < 4; ++i)
            #pragma unroll
            for (int j = 0; j < 4; ++j)
                acc[i][j] = __builtin_amdgcn_mfma_f32_16x16x32_bf16(av[i], bv[j], acc[i][j], 0, 0, 0);
        __syncthreads();                             // drains next-tile vmcnt + barrier
        cur ^= 1;
    }
    unsigned short* of = out + (size_t)(f * B_ + bt) * T_ * N_;
    #pragma unroll
    for (int i = 0; i < 4; ++i) {
        #pragma unroll
        for (int j = 0; j < 4; ++j) {
            const int n = n0 + wn + j * 16 + r16;
            const float bv2 = (s == 0) ? bias[n] : 0.0f;
            #pragma unroll
            for (int r = 0; r < 4; ++r) {
                const int m = wm + i * 16 + kb * 4 + r;
                of[(size_t)m * N_ + n] = f2bf(acc[i][j][r] + bv2);
            }
        }
    }
}

// ---------------- gating (sum 2 bf16 split-K partials) + transpose, VECTORIZED ----
// grid (T/32, N/32, F*B); uint2 (4 bf16) loads and stores
__global__ __launch_bounds__(256) void k_gate_nodes(const unsigned short* __restrict__ pa,
        const unsigned short* __restrict__ pb, unsigned short* __restrict__ nodes) {
    __shared__ float tl[32][33];
    const int bz = blockIdx.z;                       // f*B + b
    const int t0 = blockIdx.x * 32, n0 = blockIdx.y * 32;
    const size_t base = (size_t)bz * T_ * N_;
    {
        const int r = threadIdx.x >> 3;              // t row 0..31
        const int c = threadIdx.x & 7;               // n chunk of 4
        const size_t idx = base + (size_t)(t0 + r) * N_ + n0 + c * 4;
        const uint2 A0 = *(const uint2*)(pa + idx);
        const uint2 A1 = *(const uint2*)(pa + SZ_ + idx);
        const uint2 B0 = *(const uint2*)(pb + idx);
        const uint2 B1 = *(const uint2*)(pb + SZ_ + idx);
        const float av[4] = {bflo(A0.x) + bflo(A1.x), bfhi(A0.x) + bfhi(A1.x),
                             bflo(A0.y) + bflo(A1.y), bfhi(A0.y) + bfhi(A1.y)};
        const float bv[4] = {bflo(B0.x) + bflo(B1.x), bfhi(B0.x) + bfhi(B1.x),
                             bflo(B0.y) + bflo(B1.y), bfhi(B0.y) + bfhi(B1.y)};
        #pragma unroll
        for (int j = 0; j < 4; ++j)
            tl[r][c * 4 + j] = (1.0f / (1.0f + __expf(-av[j]))) * tanhf(bv[j]);
    }
    __syncthreads();
    {
        const int nr = threadIdx.x >> 3;             // n row 0..31
        const int tc = threadIdx.x & 7;              // t chunk of 4
        unsigned short pk[4];
        #pragma unroll
        for (int j = 0; j < 4; ++j) pk[j] = f2bf(tl[tc * 4 + j][nr]);
        *(uint2*)(nodes + base + (size_t)(n0 + nr) * T_ + t0 + tc * 4) = *(uint2*)pk;
    }
}

// ---------------- GAT projection GEMM (gl_lds, swizzled, Q/K/V fused, bf16 out,
// 2-phase double-buffer) ------------------------------------------------------------
__global__ __launch_bounds__(256) void k_proj_mfma(
        const unsigned short* __restrict__ nodes, const unsigned short* __restrict__ pwt,
        const float* __restrict__ qb, const float* __restrict__ kbias,
        unsigned short* __restrict__ Q, unsigned short* __restrict__ K,
        unsigned short* __restrict__ V) {
    __shared__ unsigned short As[2][128 * 32];
    __shared__ unsigned short Bs[2][128 * 32];
    const int zz = blockIdx.z;
    const int f = zz & 3;
    const int sel = zz >> 2;
    const int m0 = blockIdx.y * 128;
    const unsigned short* af = nodes + (size_t)f * M_ * T_;
    const unsigned short* wfp = pwt + (size_t)sel * F_ * T_ * T_ + (size_t)f * T_ * T_;
    const float* bias = (sel == 0) ? qb : (sel == 1 ? kbias : nullptr);
    unsigned short* out = (sel == 0) ? Q : (sel == 1 ? K : V);
    const int tid = threadIdx.x;
    const int lane = tid & 63;
    const int w = tid >> 6;
    const int wm = (w >> 1) * 64, wn = (w & 1) * 64;
    const int r16 = lane & 15, kb = lane >> 4;
    const int srow = lane >> 2;
    const int scol = (((lane & 3) ^ ((lane >> 3) & 3)) * 8);
    const int kx = (kb ^ ((r16 >> 1) & 3)) * 8;

    auto stage = [&](int buf, int kk0) {
        #pragma unroll
        for (int h = 0; h < 2; ++h) {
            const int seg = w + 4 * h;
            const int row = seg * 16 + srow;
            const unsigned short* gA = af + (size_t)(m0 + row) * T_ + kk0 + scol;
            const unsigned short* gB = wfp + (size_t)row * T_ + kk0 + scol;
            __builtin_amdgcn_global_load_lds((const AS1 unsigned int*)(const void*)gA,
                    (AS3 unsigned int*)(void*)(&As[buf][seg * 512]), 16, 0, 0);
            __builtin_amdgcn_global_load_lds((const AS1 unsigned int*)(const void*)gB,
                    (AS3 unsigned int*)(void*)(&Bs[buf][seg * 512]), 16, 0, 0);
        }
    };

    f32x4 acc[4][4] = {};
    stage(0, 0);
    __syncthreads();
    int cur = 0;
    for (int kk0 = 0; kk0 < T_; kk0 += 32) {
        if (kk0 + 32 < T_) stage(cur ^ 1, kk0 + 32);
        bf16x8 av[4], bv[4];
        #pragma unroll
        for (int i = 0; i < 4; ++i)
            av[i] = *(const bf16x8*)(&As[cur][(wm + i * 16 + r16) * 32 + kx]);
        #pragma unroll
        for (int j = 0; j < 4; ++j)
            bv[j] = *(const bf16x8*)(&Bs[cur][(wn + j * 16 + r16) * 32 + kx]);
        #pragma unroll
        for (int i = 0; i < 4; ++i)
            #pragma unroll
            for (int j = 0; j < 4; ++j)
                acc[i][j] = __builtin_amdgcn_mfma_f32_16x16x32_bf16(av[i], bv[j], acc[i][j], 0, 0, 0);
        __syncthreads();
        cur ^= 1;
    }
    const int do_l = (sel < 2);
    unsigned short* of = out + (size_t)f * M_ * T_;
    #pragma unroll
    for (int i = 0; i < 4; ++i) {
        #pragma unroll
        for (int j = 0; j < 4; ++j) {
            const int n = wn + j * 16 + r16;
            #pragma unroll
            for (int r = 0; r < 4; ++r) {
                const int m = m0 + wm + i * 16 + kb * 4 + r;
                float v = acc[i][j][r];
                if (bias) v += bias[f * T_ + n];
                if (do_l) v = lrelu(v);
                of[(size_t)m * T_ + n] = f2bf(v);
            }
        }
    }
}

// ---------------- CSR build (once; graph shared across f and layers) --------------
__device__ __forceinline__ int edge_row(const int* e, int i) { return i < E_ ? e[i] : i - E_; }
__device__ __forceinline__ int edge_col(const int* e, int i) { return i < E_ ? e[E_ + i] : i - E_; }

__global__ void k_hist(const int* __restrict__ edges, int* __restrict__ deg) {
    int i = blockIdx.x * blockDim.x + threadIdx.x;
    if (i >= EP_) return;
    atomicAdd(&deg[edge_row(edges, i)], 1);
}

__global__ __launch_bounds__(256) void k_scan(const int* __restrict__ deg,
        int* __restrict__ rowptr, int* __restrict__ cursor) {
    __shared__ int part[256];
    const int tid = threadIdx.x;
    constexpr int PER = M_ / 256;   // 24
    int loc[PER];
    int s = 0;
    #pragma unroll
    for (int j = 0; j < PER; ++j) { loc[j] = s; s += deg[tid * PER + j]; }
    part[tid] = s;
    __syncthreads();
    if (tid == 0) {
        int run = 0;
        for (int i2 = 0; i2 < 256; ++i2) { int v = part[i2]; part[i2] = run; run += v; }
        rowptr[M_] = run;
    }
    __syncthreads();
    const int off = part[tid];
    #pragma unroll
    for (int j = 0; j < PER; ++j) {
        rowptr[tid * PER + j] = off + loc[j];
        cursor[tid * PER + j] = off + loc[j];
    }
}

__global__ void k_scatter(const int* __restrict__ edges, int* __restrict__ cursor,
                          int* __restrict__ csr_col) {
    int i = blockIdx.x * blockDim.x + threadIdx.x;
    if (i >= EP_) return;
    int r = edge_row(edges, i), c = edge_col(edges, i);
    int pos = atomicAdd(&cursor[r], 1);
    csr_col[pos] = c;
}

// ---------------- fused GAT (bf16 Q/K/V, bf16 H out), VECTORIZED: lane owns a
// t-pair (uint = 2 bf16 per access); one wave per (f,row); deg==1 fast path -------
__global__ __launch_bounds__(256) void k_gat(const unsigned short* __restrict__ Q,
        const unsigned short* __restrict__ Kb, const unsigned short* __restrict__ V,
        const int* __restrict__ rowptr, const int* __restrict__ csr_col,
        unsigned short* __restrict__ H) {
    constexpr int CAP = 128;
    __shared__ float sc[4][CAP];
    const int w = threadIdx.x >> 6, lane = threadIdx.x & 63;
    const int wv = blockIdx.x * 4 + w;
    const int f = wv / M_, r = wv - f * M_;
    const int p0 = rowptr[r], p1 = rowptr[r + 1];
    unsigned short* Hr = H + ((size_t)f * M_ + r) * T_;
    if (p1 - p0 == 1) {   // self-loop only: att == 1, H = V[r]
        const unsigned short* Vr = V + ((size_t)f * M_ + r) * T_;
        *(unsigned*)(Hr + 2 * lane) = *(const unsigned*)(Vr + 2 * lane);
        return;
    }
    const unsigned short* Qr = Q + ((size_t)f * M_ + r) * T_;
    const unsigned qv = *(const unsigned*)(Qr + 2 * lane);
    const float q0 = bflo(qv), q1 = bfhi(qv);
    float mx = -3.4e38f;
    for (int j = p0; j < p1; ++j) {
        const unsigned short* Kc = Kb + ((size_t)f * M_ + csr_col[j]) * T_;
        const unsigned kv = *(const unsigned*)(Kc + 2 * lane);
        float s = q0 * bflo(kv) + q1 * bfhi(kv);
        #pragma unroll
        for (int mk = 32; mk >= 1; mk >>= 1) s += __shfl_xor(s, mk);
        s *= 0.0883883476483184f;
        if (lane == 0) sc[w][j - p0] = s;   // deg << CAP always
        mx = fmaxf(mx, s);
    }
    float den = 0.0f;
    for (int j = p0; j < p1; ++j) den += __expf(sc[w][j - p0] - mx);
    const float rden = 1.0f / den;
    float a0 = 0.0f, a1 = 0.0f;
    for (int j = p0; j < p1; ++j) {
        const int c = csr_col[j];
        const float att = __expf(sc[w][j - p0] - mx) * rden;
        const unsigned short* Vc = V + ((size_t)f * M_ + c) * T_;
        const unsigned vv = *(const unsigned*)(Vc + 2 * lane);
        a0 += att * bflo(vv);
        a1 += att * bfhi(vv);
    }
    *(unsigned*)(Hr + 2 * lane) = (unsigned)f2bf(a0) | ((unsigned)f2bf(a1) << 16);
}

// ---------------- combine: residual (bf16, in-place xTpad) + skip (bf16 sbuf) -----
// grid (T/32, N/32, B); residual read = xTpad same address as write (1:1 per thread)
__global__ __launch_bounds__(256) void k_combine_t(const unsigned short* __restrict__ Hb,
        const float* __restrict__ vb, const float* __restrict__ rw,
        const float* __restrict__ rb, const float* __restrict__ skw,
        const float* __restrict__ skb, int layer,
        unsigned short* __restrict__ xTpad, unsigned short* __restrict__ sbufp) {
    __shared__ float hl[F_][32][33];
    const int b = blockIdx.z;
    const int t0 = blockIdx.x * 32, n0 = blockIdx.y * 32;
    {
        const int nn = threadIdx.x >> 3;             // n row 0..31
        const int tc = threadIdx.x & 7;              // t chunk of 4
        #pragma unroll
        for (int g = 0; g < F_; ++g) {
            const uint2 hv = *(const uint2*)(Hb +
                ((size_t)g * M_ + b * N_ + n0 + nn) * T_ + t0 + tc * 4);
            hl[g][nn][tc * 4 + 0] = bflo(hv.x);
            hl[g][nn][tc * 4 + 1] = bfhi(hv.x);
            hl[g][nn][tc * 4 + 2] = bflo(hv.y);
            hl[g][nn][tc * 4 + 3] = bfhi(hv.y);
        }
    }
    __syncthreads();
    const int r = threadIdx.x >> 3;                  // t row 0..31
    const int nc = threadIdx.x & 7;                  // n chunk of 4
    const int t = t0 + r;
    // residual read: current-layer y (bf16) from xTpad, 4 n-elems per g
    float yv[4][F_];
    #pragma unroll
    for (int g = 0; g < F_; ++g) {
        const uint2 xv = *(const uint2*)(xTpad +
            ((size_t)(g * B_ + b) * TP_ + 4 + t) * N_ + n0 + nc * 4);
        yv[0][g] = bflo(xv.x); yv[1][g] = bfhi(xv.x);
        yv[2][g] = bflo(xv.y); yv[3][g] = bfhi(xv.y);
    }
    float o[4][F_];
    float sbv[4];
    #pragma unroll
    for (int q = 0; q < 4; ++q) {
        #pragma unroll
        for (int g = 0; g < F_; ++g) {
            float acc = hl[g][nc * 4 + q][r] + vb[g * T_ + t] + rb[g];
            #pragma unroll
            for (int f2 = 0; f2 < F_; ++f2) acc += yv[q][f2] * rw[f2 * F_ + g];
            o[q][g] = acc;
        }
        float sk = skb[layer];
        #pragma unroll
        for (int g = 0; g < F_; ++g) sk += o[q][g] * skw[layer * F_ + g];
        sbv[q] = lrelu(sk);
    }
    #pragma unroll
    for (int g = 0; g < F_; ++g) {
        unsigned short pk[4];
        #pragma unroll
        for (int q = 0; q < 4; ++q) pk[q] = f2bf(o[q][g]);
        *(uint2*)(xTpad + ((size_t)(g * B_ + b) * TP_ + 4 + t) * N_ + n0 + nc * 4)
            = *(uint2*)pk;
    }
    unsigned short sp[4];
    #pragma unroll
    for (int q = 0; q < 4; ++q) sp[q] = f2bf(sbv[q]);
    *(uint2*)(sbufp + (size_t)layer * BTN_ + ((size_t)b * T_ + t) * N_ + n0 + nc * 4)
        = *(uint2*)sp;
}

__global__ void k_final(const unsigned short* __restrict__ sbufp,
        const float* __restrict__ o1w, const float* __restrict__ o1b,
        const float* __restrict__ o2w, const float* __restrict__ o2b,
        float* __restrict__ out) {
    int i = blockIdx.x * blockDim.x + threadIdx.x;
    if (i >= BTN_) return;
    int n = i % N_, t = (i / N_) % T_, bb = i / (N_ * T_);
    float acc = o1b[0];
    #pragma unroll
    for (int dt = 0; dt < 3; ++dt) {
        int tt = t - 1 + dt;
        if (tt < 0 || tt >= T_) continue;
        #pragma unroll
        for (int dn = 0; dn < 3; ++dn) {
            int nn = n - 1 + dn;
            if (nn < 0 || nn >= N_) continue;
            const size_t base = (size_t)(bb * T_ + tt) * N_ + nn;
            #pragma unroll
            for (int l = 0; l < L_; ++l)
                acc += bf2f(sbufp[(size_t)l * BTN_ + base]) * o1w[(dt * 3 + dn) * L_ + l];
        }
    }
    float g = lrelu(acc);
    out[i] = g * o2w[0] + o2b[0];
}

extern "C" void kernel_launch(void* const* d_in, const int* in_sizes, int n_in,
                              void* d_out, int out_size, void* d_ws, size_t ws_size,
                              hipStream_t stream) {
    const float* x       = (const float*)d_in[0];
    const int*   edges   = (const int*)d_in[1];
    const float* sd_w    = (const float*)d_in[2];
    const float* sd_b    = (const float*)d_in[3];
    const float* c1w     = (const float*)d_in[4];
    const float* c1b     = (const float*)d_in[5];
    const float* c2w     = (const float*)d_in[6];
    const float* c2b     = (const float*)d_in[7];
    const float* tcn_a_w = (const float*)d_in[8];
    const float* tcn_a_b = (const float*)d_in[9];
    const float* tcn_b_w = (const float*)d_in[10];
    const float* tcn_b_b = (const float*)d_in[11];
    const float* gat_q_w = (const float*)d_in[12];
    const float* gat_q_b = (const float*)d_in[13];
    const float* gat_k_w = (const float*)d_in[14];
    const float* gat_k_b = (const float*)d_in[15];
    const float* gat_v_w = (const float*)d_in[16];
    const float* gat_v_b = (const float*)d_in[17];
    const float* res_w   = (const float*)d_in[18];
    const float* res_b   = (const float*)d_in[19];
    const float* skip_w  = (const float*)d_in[20];
    const float* skip_b  = (const float*)d_in[21];
    const float* out1_w  = (const float*)d_in[22];
    const float* out1_b  = (const float*)d_in[23];
    const float* out2_w  = (const float*)d_in[24];
    const float* out2_b  = (const float*)d_in[25];
    float* out = (float*)d_out;

    float* ws = (float*)d_ws;
    size_t off = 0;
    auto alloc = [&](size_t nf) { float* p = ws + off; off += nf; return p; };
    float* y0    = alloc(MT_);
    float* y1    = alloc(BTN_);
    unsigned short* xTpad  = (unsigned short*)alloc((size_t)F_ * B_ * TP_ * N_ / 2 + 16);
    unsigned short* nodesb = (unsigned short*)alloc(SZ_ / 2);
    unsigned short* qb16   = (unsigned short*)alloc(SZ_ / 2);
    unsigned short* kb16   = (unsigned short*)alloc(SZ_ / 2);
    unsigned short* vb16   = (unsigned short*)alloc(SZ_ / 2);
    unsigned short* Hb     = (unsigned short*)alloc(SZ_ / 2);
    unsigned short* pa     = (unsigned short*)alloc(SZ_);       // 2 partial planes
    unsigned short* pb     = (unsigned short*)alloc(SZ_);       // 2 partial planes
    unsigned short* sbufp  = (unsigned short*)alloc((size_t)BTN_ * L_ / 2);
    unsigned short* wat3 = (unsigned short*)alloc((size_t)L_ * F_ * KTCN_ * N_ / 2);
    unsigned short* wbt3 = (unsigned short*)alloc((size_t)L_ * F_ * KTCN_ * N_ / 2);
    unsigned short* pwt3 = (unsigned short*)alloc((size_t)L_ * 3 * F_ * T_ * T_ / 2);
    int* rowptr  = (int*)alloc(M_ + 1);
    int* cursor  = (int*)alloc(M_);
    int* deg     = (int*)alloc(M_);
    int* csr_col = (int*)alloc(EP_);
    (void)ws_size; (void)in_sizes; (void)n_in; (void)out_size;

    // zero padded activation buffer once (pad rows stay zero forever)
    hipMemsetAsync(xTpad, 0, (size_t)F_ * B_ * TP_ * N_ * 2, stream);
    // CSR build (graph is layer/f independent)
    hipMemsetAsync(deg, 0, M_ * 4, stream);
    k_hist<<<(EP_ + 255) / 256, 256, 0, stream>>>(edges, deg);
    k_scan<<<1, 256, 0, stream>>>(deg, rowptr, cursor);
    k_scatter<<<(EP_ + 255) / 256, 256, 0, stream>>>(edges, cursor, csr_col);

    // ALL weight prep hoisted: TCN (a/b, 3 layers) + proj (q/k/v, 3 layers)
    dim3 gw2(KTCN_ / 32, 8 * L_);
    k_convT2<<<gw2, 256, 0, stream>>>(tcn_a_w, tcn_b_w, wat3, wbt3);
    dim3 gpw(T_ / 32, T_ / 32, 12 * L_);
    k_convTproj<<<gpw, 256, 0, stream>>>(gat_q_w, gat_k_w, gat_v_w, pwt3);

    // shunt
    k_dense<<<(B_ * T_ + 255) / 256, 256, 0, stream>>>(x, sd_w, sd_b, y0);
    k_conv1<<<(BTN_ + 255) / 256, 256, 0, stream>>>(y0, c1w, c1b, y1);
    k_conv2w<<<(BTN_ + 255) / 256, 256, 0, stream>>>(y1, c2w, c2b, xTpad);

    for (int layer = 0; layer < L_; ++layer) {
        const float* ba = tcn_a_b + (size_t)layer * F_ * N_;
        const float* bb = tcn_b_b + (size_t)layer * F_ * N_;
        const float* qb = gat_q_b + (size_t)layer * F_ * T_;
        const float* kbias = gat_k_b + (size_t)layer * F_ * T_;
        const float* vb = gat_v_b + (size_t)layer * F_ * T_;
        const float* rw = res_w + (size_t)layer * F_ * F_;
        const float* rb = res_b + (size_t)layer * F_;
        const unsigned short* wat = wat3 + (size_t)layer * F_ * KTCN_ * N_;
        const unsigned short* wbt = wbt3 + (size_t)layer * F_ * KTCN_ * N_;
        const unsigned short* pwt = pwt3 + (size_t)layer * 3 * F_ * T_ * T_;

        // TCN GEMMs: 128x128 tile, a/b fused, split-K=2, XCD-aware 1-D grid, dbuf
        k_tcn_mfma<<<768, 256, 0, stream>>>(xTpad, wat, wbt, ba, bb, pa, pb);
        // gating (sum 2 partials) + transpose -> bf16 nodes
        dim3 gg(T_ / 32, N_ / 32, F_ * B_);
        k_gate_nodes<<<gg, 256, 0, stream>>>(pa, pb, nodesb);
        // projections fused: Q/K/V -> bf16, dbuf
        dim3 gp(1, M_ / 128, 12);
        k_proj_mfma<<<gp, 256, 0, stream>>>(nodesb, pwt, qb, kbias, qb16, kb16, vb16);
        // fused GAT (no atomics, no memsets), bf16 H, deg==1 fast path
        k_gat<<<(F_ * M_) / 4, 256, 0, stream>>>(qb16, kb16, vb16, rowptr, csr_col, Hb);
        // combine: residual in-place on xTpad (bf16) + bf16 skip plane
        dim3 gc(T_ / 32, N_ / 32, B_);
        k_combine_t<<<gc, 256, 0, stream>>>(Hb, vb, rw, rb, skip_w, skip_b,
                layer, xTpad, sbufp);
    }
    k_final<<<(BTN_ + 255) / 256, 256, 0, stream>>>(sbufp, out1_w, out1_b, out2_w, out2_b, out);
}